// Round 10
// baseline (360.699 us; speedup 1.0000x reference)
//
#include <hip/hip_runtime.h>
#include <hip/hip_bf16.h>
#include <cmath>

// NPHierarchicalTransitionPrior — round 10: R3 structure (validated, 149 µs),
// LDS shrunk 24->16 KB by letting U1m reuse H1's buffer (H1 dead after
// barrier 2; d1 lives in registers). Costs one extra end-of-pass barrier,
// buys 8 resident blocks/CU (was 6). Math bit-identical to R3.
// Block = one (layer L, unit d, batch row b); 8 passes x 64 samples.
//   GEMM1: H1pre = W1 (64xIN pad32) x V(32x64)   [M-split over 4 waves]
//   GEMM2: H2pre = W2 (64x64) x H1               [M-split]
//   GEMM3: U1    = W2^T x U2                     [M-split]
//   GEMM4: G     = W1^T x (D1.U1)                [N-split]
// LDS: buf0 = H1 then U1m (reuse), buf1 = U2. B-frag-native layout,
// XOR-swizzled: byte(k,n) = (k>>3)*1024 + n*16 + (k&7)*2,
//               bits[6:4] ^= ((k>>3)&3)<<1 ^ ((n>>3)&1)

namespace {

using bf16x8 = __attribute__((ext_vector_type(8))) short;
using f32x4  = __attribute__((ext_vector_type(4))) float;
using f32x2  = __attribute__((ext_vector_type(2))) float;
using bf2    = __attribute__((ext_vector_type(2))) __bf16;
using u32x2  = __attribute__((ext_vector_type(2))) unsigned;
using u32x4  = __attribute__((ext_vector_type(4))) unsigned;

constexpr int NB = 256, NT = 512, TROW = 513, DIN = 16, HID = 64;
constexpr int NSAMP = NB * NT;                                // 131072
constexpr size_t OFF_SUMLOG = (size_t)NSAMP * DIN;            // 2097152
constexpr size_t OFF_H0     = OFF_SUMLOG + NB;                // 2097408
constexpr size_t OFF_H1     = OFF_H0 + (size_t)8 * NSAMP * 8; // 10486016

struct SMem {
    alignas(16) char frag[2 * 8192];   // buf0: H1 / U1m (reused) | buf1: U2
    float sresW[256];                  // per-wave residual partials [w][n]
    float slogW[4];
};

__device__ __forceinline__ short b16(float f) {
    return __builtin_bit_cast(short, (__bf16)f);
}
// pair convert -> v_cvt_pk_bf16_f32
__device__ __forceinline__ unsigned pk2(float a, float b) {
    f32x2 t{a, b};
    return __builtin_bit_cast(unsigned, __builtin_convertvector(t, bf2));
}
__device__ __forceinline__ bf16x8 mkfrag(unsigned a, unsigned b, unsigned c, unsigned d) {
    u32x4 t{a, b, c, d};
    return __builtin_bit_cast(bf16x8, t);
}
__device__ __forceinline__ f32x4 mfma16(bf16x8 a, bf16x8 b, f32x4 c) {
    return __builtin_amdgcn_mfma_f32_16x16x32_bf16(a, b, c, 0, 0, 0);
}

template<int L, int IN>
__device__ __forceinline__ void mlp_impl(
    SMem& sm, int d, int b,
    const float* __restrict__ x,
    const float* __restrict__ gW1, const float* __restrict__ gb1,
    const float* __restrict__ gW2, const float* __restrict__ gb2,
    const float* __restrict__ gW3, const float* __restrict__ gb3,
    float* __restrict__ out)
{
    const int tid = threadIdx.x;
    const int w = tid >> 6, lane = tid & 63;
    const int q = lane >> 4, r = lane & 15;

    // ---- swizzled LDS byte bases (constant per thread)
    // reads: element k=32ks+8q+e, col n=16g+r  ->  rbase + ks*4096 + g*256 (+buf)
    const int rbase = (q * 1024 + r * 16)
                    ^ ((((q & 3) << 1) ^ ((r >> 3) & 1)) << 4);
    // writes: rows k0=16w+4q..+3, col n=16g+r  ->  wbase + g*256 (+buf)
    const int q4w = 2 * w + (q >> 1);
    const int wbase = (q4w * 1024 + r * 16 + (q & 1) * 8)
                    ^ ((((q4w & 3) << 1) ^ ((r >> 3) & 1)) << 4);
    char* fr = sm.frag;

    // ---- hoist A-fragments + consts to registers (once per block)
    bf16x8 aW1;  // A[j=16w+r][k=8q+e] of W1, zero-padded past IN
    {
        const float* p = gW1 + (size_t)(d * HID + 16 * w + r) * IN;
        #pragma unroll
        for (int e = 0; e < 8; ++e) {
            int k = 8 * q + e;
            aW1[e] = (k < IN) ? b16(p[k]) : (short)0;
        }
    }
    bf16x8 aW2[2], aW2T[2];
    #pragma unroll
    for (int ks = 0; ks < 2; ++ks) {
        const float* p = gW2 + (size_t)(d * HID + 16 * w + r) * HID + 32 * ks + 8 * q;
        #pragma unroll
        for (int e = 0; e < 8; ++e) aW2[ks][e] = b16(p[e]);
        const float* pt = gW2 + (size_t)d * HID * HID
                        + (size_t)(32 * ks + 8 * q) * HID + 16 * w + r;
        #pragma unroll
        for (int e = 0; e < 8; ++e) aW2T[ks][e] = b16(pt[(size_t)e * HID]);
    }
    constexpr int NMT = (IN > 16) ? 2 : 1;
    bf16x8 aW1T[NMT][2];  // A[i=16mt+r][k=8q+e+32ks] of W1^T
    #pragma unroll
    for (int mt = 0; mt < NMT; ++mt) {
        const int i = 16 * mt + r;
        #pragma unroll
        for (int ks = 0; ks < 2; ++ks) {
            const float* pt = gW1 + (size_t)d * HID * IN
                            + (size_t)(32 * ks + 8 * q) * IN + i;
            #pragma unroll
            for (int e = 0; e < 8; ++e)
                aW1T[mt][ks][e] = (i < IN) ? b16(pt[(size_t)e * IN]) : (short)0;
        }
    }
    const f32x4 c1init = *reinterpret_cast<const f32x4*>(gb1 + d * HID + 16 * w + 4 * q);
    const f32x4 c2init = *reinterpret_cast<const f32x4*>(gb2 + d * HID + 16 * w + 4 * q);
    const f32x4 w3r    = *reinterpret_cast<const f32x4*>(gW3 + d * HID + 16 * w + 4 * q);
    f32x4 w3s;
    #pragma unroll
    for (int e = 0; e < 4; ++e) w3s[e] = 0.01f * w3r[e];
    const float b3v = gb3[d];

    const float* xb = x + (size_t)b * TROW * DIN;
    float lgacc = 0.0f;

    for (int ps = 0; ps < 8; ++ps) {
        const int tbase = ps * 64;
        float d1v[16];   // leaky'(H1pre) for this thread's 16 (row,col) cells

        // ---- GEMM1: H1pre = W1 V + b1 ; H1 = pre * leaky'(pre) -> buf0
        #pragma unroll
        for (int g = 0; g < 4; ++g) {
            const float* xr = xb + (size_t)(tbase + 16 * g + r) * DIN;
            float f0=0,f1=0,f2=0,f3=0,f4=0,f5=0,f6=0,f7=0;
            if constexpr (L == 0) {
                if (q == 0) {                       // yy[8..15]
                    f32x4 u0 = *reinterpret_cast<const f32x4*>(xr + 8);
                    f32x4 u1 = *reinterpret_cast<const f32x4*>(xr + 12);
                    f0=u0[0]; f1=u0[1]; f2=u0[2]; f3=u0[3];
                    f4=u1[0]; f5=u1[1]; f6=u1[2]; f7=u1[3];
                } else if (q == 1) {                // xx[8+d]
                    f0 = xr[DIN + 8 + d];
                }
            } else {
                if (q == 0) {                       // yy[0..7]
                    f32x4 u0 = *reinterpret_cast<const f32x4*>(xr);
                    f32x4 u1 = *reinterpret_cast<const f32x4*>(xr + 4);
                    f0=u0[0]; f1=u0[1]; f2=u0[2]; f3=u0[3];
                    f4=u1[0]; f5=u1[1]; f6=u1[2]; f7=u1[3];
                } else if (q == 1) {                // xx[8..15]
                    f32x4 u0 = *reinterpret_cast<const f32x4*>(xr + 24);
                    f32x4 u1 = *reinterpret_cast<const f32x4*>(xr + 28);
                    f0=u0[0]; f1=u0[1]; f2=u0[2]; f3=u0[3];
                    f4=u1[0]; f5=u1[1]; f6=u1[2]; f7=u1[3];
                } else if (q == 2) {                // xx[d]
                    f0 = xr[DIN + d];
                }
            }
            bf16x8 bv = mkfrag(pk2(f0,f1), pk2(f2,f3), pk2(f4,f5), pk2(f6,f7));
            f32x4 acc = mfma16(aW1, bv, c1init);
            float hh[4];
            #pragma unroll
            for (int e = 0; e < 4; ++e) {
                float dd = (acc[e] >= 0.0f) ? 1.0f : 0.01f;
                d1v[g * 4 + e] = dd;
                hh[e] = acc[e] * dd;
            }
            *reinterpret_cast<u32x2*>(fr + wbase + g * 256) =
                u32x2{pk2(hh[0], hh[1]), pk2(hh[2], hh[3])};
        }
        __syncthreads();   // (1) H1 complete

        // ---- GEMM2: H2pre = W2 H1 + b2 ; residual partial + U2 -> buf1
        #pragma unroll
        for (int g = 0; g < 4; ++g) {
            f32x4 acc = c2init;
            acc = mfma16(aW2[0], *reinterpret_cast<const bf16x8*>(fr + rbase + g*256), acc);
            acc = mfma16(aW2[1], *reinterpret_cast<const bf16x8*>(fr + rbase + 4096 + g*256), acc);
            float pr = 0.0f, u2v[4];
            #pragma unroll
            for (int e = 0; e < 4; ++e) {
                u2v[e] = (acc[e] >= 0.0f) ? w3r[e] : w3s[e];   // w3*leaky'
                pr = fmaf(u2v[e], acc[e], pr);                 // w3*h2 == u2*pre
            }
            pr += __shfl_xor(pr, 16, 64);
            pr += __shfl_xor(pr, 32, 64);
            if (q == 0) sm.sresW[w * 64 + 16 * g + r] = pr;
            *reinterpret_cast<u32x2*>(fr + 8192 + wbase + g * 256) =
                u32x2{pk2(u2v[0], u2v[1]), pk2(u2v[2], u2v[3])};
        }
        __syncthreads();   // (2) U2 complete, H1 dead -> buf0 reusable

        // ---- GEMM3: U1 = W2^T U2 ; mask by d1 -> buf0 (reuses H1's buffer)
        #pragma unroll
        for (int g = 0; g < 4; ++g) {
            f32x4 acc = {0.0f, 0.0f, 0.0f, 0.0f};
            acc = mfma16(aW2T[0], *reinterpret_cast<const bf16x8*>(fr + 8192 + rbase + g*256), acc);
            acc = mfma16(aW2T[1], *reinterpret_cast<const bf16x8*>(fr + 8192 + rbase + 4096 + g*256), acc);
            float u0 = acc[0] * d1v[g*4+0], u1 = acc[1] * d1v[g*4+1];
            float u2 = acc[2] * d1v[g*4+2], u3 = acc[3] * d1v[g*4+3];
            *reinterpret_cast<u32x2*>(fr + wbase + g * 256) =
                u32x2{pk2(u0, u1), pk2(u2, u3)};
        }
        __syncthreads();   // (3) U1m complete

        // ---- GEMM4 (N-split: wave w owns samples n=16w+r): G = W1^T (D1.U1)
        {
            const size_t nglob = (size_t)b * NT + tbase + 16 * w + r;
            bf16x8 bu0 = *reinterpret_cast<const bf16x8*>(fr + rbase + w * 256);
            bf16x8 bu1 = *reinterpret_cast<const bf16x8*>(fr + rbase + 4096 + w * 256);
            f32x4 g0 = {0.0f, 0.0f, 0.0f, 0.0f};
            g0 = mfma16(aW1T[0][0], bu0, g0);
            g0 = mfma16(aW1T[0][1], bu1, g0);
            if constexpr (L == 1) {
                f32x4 g1 = {0.0f, 0.0f, 0.0f, 0.0f};
                g1 = mfma16(aW1T[1][0], bu0, g1);
                g1 = mfma16(aW1T[1][1], bu1, g1);
                *reinterpret_cast<f32x4*>(out + OFF_H1 + ((size_t)d * NSAMP + nglob) * 16 + 4 * q) = g0;
                if (q == 0) lgacc += logf(fabsf(g1[0]));       // row 16 = xcol
            } else {
                if (q < 2)
                    *reinterpret_cast<f32x4*>(out + OFF_H0 + ((size_t)d * NSAMP + nglob) * 8 + 4 * q) = g0;
                if (q == 2) lgacc += logf(fabsf(g0[0]));       // row 8 = xcol
            }
        }
        // ---- residual store (sresW complete since barrier 2)
        if (tid < 64) {
            float rs = sm.sresW[tid] + sm.sresW[64 + tid]
                     + sm.sresW[128 + tid] + sm.sresW[192 + tid] + b3v;
            out[((size_t)b * NT + tbase + tid) * DIN + (L * 8 + d)] = rs;
        }
        __syncthreads();   // (4) buf0 reads done -> next pass may overwrite
    }

    // ---- block epilogue: logdet reduction + one global atomic per block
    float v = lgacc;
    #pragma unroll
    for (int off = 1; off < 64; off <<= 1) v += __shfl_xor(v, off, 64);
    if (lane == 0) sm.slogW[w] = v;
    __syncthreads();
    if (tid == 0)
        atomicAdd(out + OFF_SUMLOG + b,
                  sm.slogW[0] + sm.slogW[1] + sm.slogW[2] + sm.slogW[3]);
}

__global__ void zero_sumlog_kernel(float* __restrict__ out) {
    out[OFF_SUMLOG + threadIdx.x] = 0.0f;
}

__global__ __launch_bounds__(256, 8) void mlp_mfma_kernel(
    const float* __restrict__ x,
    const float* __restrict__ l0W1, const float* __restrict__ l0b1,
    const float* __restrict__ l0W2, const float* __restrict__ l0b2,
    const float* __restrict__ l0W3, const float* __restrict__ l0b3,
    const float* __restrict__ l1W1, const float* __restrict__ l1b1,
    const float* __restrict__ l1W2, const float* __restrict__ l1b2,
    const float* __restrict__ l1W3, const float* __restrict__ l1b3,
    float* __restrict__ out)
{
    __shared__ SMem sm;
    // XCD-aware decode: XCD k owns batch rows [32k, 32k+32) for all 16 (L,d)
    // units -> x slice + residual lines + weights live in one L2.
    const int xcd = blockIdx.x & 7;
    const int idx = blockIdx.x >> 3;         // 0..511
    const int b   = xcd * 32 + (idx & 31);
    const int uld = idx >> 5;                // 0..15
    if (uld < 8)
        mlp_impl<0, 9>(sm, uld, b, x, l0W1, l0b1, l0W2, l0b2, l0W3, l0b3, out);
    else
        mlp_impl<1, 17>(sm, uld - 8, b, x, l1W1, l1b1, l1W2, l1b2, l1W3, l1b3, out);
}

} // namespace

extern "C" void kernel_launch(void* const* d_in, const int* in_sizes, int n_in,
                              void* d_out, int out_size, void* d_ws, size_t ws_size,
                              hipStream_t stream) {
    const float* x = (const float*)d_in[0];
    // d_in[1] = alphas — unused by the reference outputs
    float* out = (float*)d_out;

    zero_sumlog_kernel<<<1, 256, 0, stream>>>(out);
    mlp_mfma_kernel<<<4096, 256, 0, stream>>>(
        x,
        (const float*)d_in[2],  (const float*)d_in[3],  (const float*)d_in[4],
        (const float*)d_in[5],  (const float*)d_in[6],  (const float*)d_in[7],
        (const float*)d_in[8],  (const float*)d_in[9],  (const float*)d_in[10],
        (const float*)d_in[11], (const float*)d_in[12], (const float*)d_in[13],
        out);
}

// Round 11
// 151.212 us; speedup vs baseline: 2.3854x; 2.3854x over previous
//
#include <hip/hip_runtime.h>
#include <hip/hip_bf16.h>
#include <cmath>

// NPHierarchicalTransitionPrior — round 11: R10's 16 KB-LDS layout (U1m reuses
// H1's buffer; +1 end-of-pass barrier) with R3's natural register budget
// (__launch_bounds__(256,3) -> ~56 VGPR, no scratch spill). Math bit-identical
// to R3. R10's failure was the forced (256,8) bound: VGPR=32 -> d1v/frags in
// scratch -> 576 MB FETCH. This round re-tests the occupancy hypothesis clean.
// Block = one (layer L, unit d, batch row b); 8 passes x 64 samples.
//   GEMM1: H1pre = W1 (64xIN pad32) x V(32x64)   [M-split over 4 waves]
//   GEMM2: H2pre = W2 (64x64) x H1               [M-split]
//   GEMM3: U1    = W2^T x U2                     [M-split]
//   GEMM4: G     = W1^T x (D1.U1)                [N-split]
// LDS: buf0 = H1 then U1m (reuse), buf1 = U2. B-frag-native layout,
// XOR-swizzled: byte(k,n) = (k>>3)*1024 + n*16 + (k&7)*2,
//               bits[6:4] ^= ((k>>3)&3)<<1 ^ ((n>>3)&1)

namespace {

using bf16x8 = __attribute__((ext_vector_type(8))) short;
using f32x4  = __attribute__((ext_vector_type(4))) float;
using f32x2  = __attribute__((ext_vector_type(2))) float;
using bf2    = __attribute__((ext_vector_type(2))) __bf16;
using u32x2  = __attribute__((ext_vector_type(2))) unsigned;
using u32x4  = __attribute__((ext_vector_type(4))) unsigned;

constexpr int NB = 256, NT = 512, TROW = 513, DIN = 16, HID = 64;
constexpr int NSAMP = NB * NT;                                // 131072
constexpr size_t OFF_SUMLOG = (size_t)NSAMP * DIN;            // 2097152
constexpr size_t OFF_H0     = OFF_SUMLOG + NB;                // 2097408
constexpr size_t OFF_H1     = OFF_H0 + (size_t)8 * NSAMP * 8; // 10486016

struct SMem {
    alignas(16) char frag[2 * 8192];   // buf0: H1 / U1m (reused) | buf1: U2
    float sresW[256];                  // per-wave residual partials [w][n]
    float slogW[4];
};

__device__ __forceinline__ short b16(float f) {
    return __builtin_bit_cast(short, (__bf16)f);
}
// pair convert -> v_cvt_pk_bf16_f32
__device__ __forceinline__ unsigned pk2(float a, float b) {
    f32x2 t{a, b};
    return __builtin_bit_cast(unsigned, __builtin_convertvector(t, bf2));
}
__device__ __forceinline__ bf16x8 mkfrag(unsigned a, unsigned b, unsigned c, unsigned d) {
    u32x4 t{a, b, c, d};
    return __builtin_bit_cast(bf16x8, t);
}
__device__ __forceinline__ f32x4 mfma16(bf16x8 a, bf16x8 b, f32x4 c) {
    return __builtin_amdgcn_mfma_f32_16x16x32_bf16(a, b, c, 0, 0, 0);
}

template<int L, int IN>
__device__ __forceinline__ void mlp_impl(
    SMem& sm, int d, int b,
    const float* __restrict__ x,
    const float* __restrict__ gW1, const float* __restrict__ gb1,
    const float* __restrict__ gW2, const float* __restrict__ gb2,
    const float* __restrict__ gW3, const float* __restrict__ gb3,
    float* __restrict__ out)
{
    const int tid = threadIdx.x;
    const int w = tid >> 6, lane = tid & 63;
    const int q = lane >> 4, r = lane & 15;

    // ---- swizzled LDS byte bases (constant per thread)
    // reads: element k=32ks+8q+e, col n=16g+r  ->  rbase + ks*4096 + g*256 (+buf)
    const int rbase = (q * 1024 + r * 16)
                    ^ ((((q & 3) << 1) ^ ((r >> 3) & 1)) << 4);
    // writes: rows k0=16w+4q..+3, col n=16g+r  ->  wbase + g*256 (+buf)
    const int q4w = 2 * w + (q >> 1);
    const int wbase = (q4w * 1024 + r * 16 + (q & 1) * 8)
                    ^ ((((q4w & 3) << 1) ^ ((r >> 3) & 1)) << 4);
    char* fr = sm.frag;

    // ---- hoist A-fragments + consts to registers (once per block)
    bf16x8 aW1;  // A[j=16w+r][k=8q+e] of W1, zero-padded past IN
    {
        const float* p = gW1 + (size_t)(d * HID + 16 * w + r) * IN;
        #pragma unroll
        for (int e = 0; e < 8; ++e) {
            int k = 8 * q + e;
            aW1[e] = (k < IN) ? b16(p[k]) : (short)0;
        }
    }
    bf16x8 aW2[2], aW2T[2];
    #pragma unroll
    for (int ks = 0; ks < 2; ++ks) {
        const float* p = gW2 + (size_t)(d * HID + 16 * w + r) * HID + 32 * ks + 8 * q;
        #pragma unroll
        for (int e = 0; e < 8; ++e) aW2[ks][e] = b16(p[e]);
        const float* pt = gW2 + (size_t)d * HID * HID
                        + (size_t)(32 * ks + 8 * q) * HID + 16 * w + r;
        #pragma unroll
        for (int e = 0; e < 8; ++e) aW2T[ks][e] = b16(pt[(size_t)e * HID]);
    }
    constexpr int NMT = (IN > 16) ? 2 : 1;
    bf16x8 aW1T[NMT][2];  // A[i=16mt+r][k=8q+e+32ks] of W1^T
    #pragma unroll
    for (int mt = 0; mt < NMT; ++mt) {
        const int i = 16 * mt + r;
        #pragma unroll
        for (int ks = 0; ks < 2; ++ks) {
            const float* pt = gW1 + (size_t)d * HID * IN
                            + (size_t)(32 * ks + 8 * q) * IN + i;
            #pragma unroll
            for (int e = 0; e < 8; ++e)
                aW1T[mt][ks][e] = (i < IN) ? b16(pt[(size_t)e * IN]) : (short)0;
        }
    }
    const f32x4 c1init = *reinterpret_cast<const f32x4*>(gb1 + d * HID + 16 * w + 4 * q);
    const f32x4 c2init = *reinterpret_cast<const f32x4*>(gb2 + d * HID + 16 * w + 4 * q);
    const f32x4 w3r    = *reinterpret_cast<const f32x4*>(gW3 + d * HID + 16 * w + 4 * q);
    f32x4 w3s;
    #pragma unroll
    for (int e = 0; e < 4; ++e) w3s[e] = 0.01f * w3r[e];
    const float b3v = gb3[d];

    const float* xb = x + (size_t)b * TROW * DIN;
    float lgacc = 0.0f;

    for (int ps = 0; ps < 8; ++ps) {
        const int tbase = ps * 64;
        float d1v[16];   // leaky'(H1pre) for this thread's 16 (row,col) cells

        // ---- GEMM1: H1pre = W1 V + b1 ; H1 = pre * leaky'(pre) -> buf0
        #pragma unroll
        for (int g = 0; g < 4; ++g) {
            const float* xr = xb + (size_t)(tbase + 16 * g + r) * DIN;
            float f0=0,f1=0,f2=0,f3=0,f4=0,f5=0,f6=0,f7=0;
            if constexpr (L == 0) {
                if (q == 0) {                       // yy[8..15]
                    f32x4 u0 = *reinterpret_cast<const f32x4*>(xr + 8);
                    f32x4 u1 = *reinterpret_cast<const f32x4*>(xr + 12);
                    f0=u0[0]; f1=u0[1]; f2=u0[2]; f3=u0[3];
                    f4=u1[0]; f5=u1[1]; f6=u1[2]; f7=u1[3];
                } else if (q == 1) {                // xx[8+d]
                    f0 = xr[DIN + 8 + d];
                }
            } else {
                if (q == 0) {                       // yy[0..7]
                    f32x4 u0 = *reinterpret_cast<const f32x4*>(xr);
                    f32x4 u1 = *reinterpret_cast<const f32x4*>(xr + 4);
                    f0=u0[0]; f1=u0[1]; f2=u0[2]; f3=u0[3];
                    f4=u1[0]; f5=u1[1]; f6=u1[2]; f7=u1[3];
                } else if (q == 1) {                // xx[8..15]
                    f32x4 u0 = *reinterpret_cast<const f32x4*>(xr + 24);
                    f32x4 u1 = *reinterpret_cast<const f32x4*>(xr + 28);
                    f0=u0[0]; f1=u0[1]; f2=u0[2]; f3=u0[3];
                    f4=u1[0]; f5=u1[1]; f6=u1[2]; f7=u1[3];
                } else if (q == 2) {                // xx[d]
                    f0 = xr[DIN + d];
                }
            }
            bf16x8 bv = mkfrag(pk2(f0,f1), pk2(f2,f3), pk2(f4,f5), pk2(f6,f7));
            f32x4 acc = mfma16(aW1, bv, c1init);
            float hh[4];
            #pragma unroll
            for (int e = 0; e < 4; ++e) {
                float dd = (acc[e] >= 0.0f) ? 1.0f : 0.01f;
                d1v[g * 4 + e] = dd;
                hh[e] = acc[e] * dd;
            }
            *reinterpret_cast<u32x2*>(fr + wbase + g * 256) =
                u32x2{pk2(hh[0], hh[1]), pk2(hh[2], hh[3])};
        }
        __syncthreads();   // (1) H1 complete

        // ---- GEMM2: H2pre = W2 H1 + b2 ; residual partial + U2 -> buf1
        #pragma unroll
        for (int g = 0; g < 4; ++g) {
            f32x4 acc = c2init;
            acc = mfma16(aW2[0], *reinterpret_cast<const bf16x8*>(fr + rbase + g*256), acc);
            acc = mfma16(aW2[1], *reinterpret_cast<const bf16x8*>(fr + rbase + 4096 + g*256), acc);
            float pr = 0.0f, u2v[4];
            #pragma unroll
            for (int e = 0; e < 4; ++e) {
                u2v[e] = (acc[e] >= 0.0f) ? w3r[e] : w3s[e];   // w3*leaky'
                pr = fmaf(u2v[e], acc[e], pr);                 // w3*h2 == u2*pre
            }
            pr += __shfl_xor(pr, 16, 64);
            pr += __shfl_xor(pr, 32, 64);
            if (q == 0) sm.sresW[w * 64 + 16 * g + r] = pr;
            *reinterpret_cast<u32x2*>(fr + 8192 + wbase + g * 256) =
                u32x2{pk2(u2v[0], u2v[1]), pk2(u2v[2], u2v[3])};
        }
        __syncthreads();   // (2) U2 complete, H1 dead -> buf0 reusable

        // ---- GEMM3: U1 = W2^T U2 ; mask by d1 -> buf0 (reuses H1's buffer)
        #pragma unroll
        for (int g = 0; g < 4; ++g) {
            f32x4 acc = {0.0f, 0.0f, 0.0f, 0.0f};
            acc = mfma16(aW2T[0], *reinterpret_cast<const bf16x8*>(fr + 8192 + rbase + g*256), acc);
            acc = mfma16(aW2T[1], *reinterpret_cast<const bf16x8*>(fr + 8192 + rbase + 4096 + g*256), acc);
            float u0 = acc[0] * d1v[g*4+0], u1 = acc[1] * d1v[g*4+1];
            float u2 = acc[2] * d1v[g*4+2], u3 = acc[3] * d1v[g*4+3];
            *reinterpret_cast<u32x2*>(fr + wbase + g * 256) =
                u32x2{pk2(u0, u1), pk2(u2, u3)};
        }
        __syncthreads();   // (3) U1m complete

        // ---- GEMM4 (N-split: wave w owns samples n=16w+r): G = W1^T (D1.U1)
        {
            const size_t nglob = (size_t)b * NT + tbase + 16 * w + r;
            bf16x8 bu0 = *reinterpret_cast<const bf16x8*>(fr + rbase + w * 256);
            bf16x8 bu1 = *reinterpret_cast<const bf16x8*>(fr + rbase + 4096 + w * 256);
            f32x4 g0 = {0.0f, 0.0f, 0.0f, 0.0f};
            g0 = mfma16(aW1T[0][0], bu0, g0);
            g0 = mfma16(aW1T[0][1], bu1, g0);
            if constexpr (L == 1) {
                f32x4 g1 = {0.0f, 0.0f, 0.0f, 0.0f};
                g1 = mfma16(aW1T[1][0], bu0, g1);
                g1 = mfma16(aW1T[1][1], bu1, g1);
                *reinterpret_cast<f32x4*>(out + OFF_H1 + ((size_t)d * NSAMP + nglob) * 16 + 4 * q) = g0;
                if (q == 0) lgacc += logf(fabsf(g1[0]));       // row 16 = xcol
            } else {
                if (q < 2)
                    *reinterpret_cast<f32x4*>(out + OFF_H0 + ((size_t)d * NSAMP + nglob) * 8 + 4 * q) = g0;
                if (q == 2) lgacc += logf(fabsf(g0[0]));       // row 8 = xcol
            }
        }
        // ---- residual store (sresW complete since barrier 2)
        if (tid < 64) {
            float rs = sm.sresW[tid] + sm.sresW[64 + tid]
                     + sm.sresW[128 + tid] + sm.sresW[192 + tid] + b3v;
            out[((size_t)b * NT + tbase + tid) * DIN + (L * 8 + d)] = rs;
        }
        __syncthreads();   // (4) buf0 reads done -> next pass may overwrite
    }

    // ---- block epilogue: logdet reduction + one global atomic per block
    float v = lgacc;
    #pragma unroll
    for (int off = 1; off < 64; off <<= 1) v += __shfl_xor(v, off, 64);
    if (lane == 0) sm.slogW[w] = v;
    __syncthreads();
    if (tid == 0)
        atomicAdd(out + OFF_SUMLOG + b,
                  sm.slogW[0] + sm.slogW[1] + sm.slogW[2] + sm.slogW[3]);
}

__global__ void zero_sumlog_kernel(float* __restrict__ out) {
    out[OFF_SUMLOG + threadIdx.x] = 0.0f;
}

__global__ __launch_bounds__(256, 3) void mlp_mfma_kernel(
    const float* __restrict__ x,
    const float* __restrict__ l0W1, const float* __restrict__ l0b1,
    const float* __restrict__ l0W2, const float* __restrict__ l0b2,
    const float* __restrict__ l0W3, const float* __restrict__ l0b3,
    const float* __restrict__ l1W1, const float* __restrict__ l1b1,
    const float* __restrict__ l1W2, const float* __restrict__ l1b2,
    const float* __restrict__ l1W3, const float* __restrict__ l1b3,
    float* __restrict__ out)
{
    __shared__ SMem sm;
    // XCD-aware decode: XCD k owns batch rows [32k, 32k+32) for all 16 (L,d)
    // units -> x slice + residual lines + weights live in one L2.
    const int xcd = blockIdx.x & 7;
    const int idx = blockIdx.x >> 3;         // 0..511
    const int b   = xcd * 32 + (idx & 31);
    const int uld = idx >> 5;                // 0..15
    if (uld < 8)
        mlp_impl<0, 9>(sm, uld, b, x, l0W1, l0b1, l0W2, l0b2, l0W3, l0b3, out);
    else
        mlp_impl<1, 17>(sm, uld - 8, b, x, l1W1, l1b1, l1W2, l1b2, l1W3, l1b3, out);
}

} // namespace

extern "C" void kernel_launch(void* const* d_in, const int* in_sizes, int n_in,
                              void* d_out, int out_size, void* d_ws, size_t ws_size,
                              hipStream_t stream) {
    const float* x = (const float*)d_in[0];
    // d_in[1] = alphas — unused by the reference outputs
    float* out = (float*)d_out;

    zero_sumlog_kernel<<<1, 256, 0, stream>>>(out);
    mlp_mfma_kernel<<<4096, 256, 0, stream>>>(
        x,
        (const float*)d_in[2],  (const float*)d_in[3],  (const float*)d_in[4],
        (const float*)d_in[5],  (const float*)d_in[6],  (const float*)d_in[7],
        (const float*)d_in[8],  (const float*)d_in[9],  (const float*)d_in[10],
        (const float*)d_in[11], (const float*)d_in[12], (const float*)d_in[13],
        out);
}